// Round 5
// baseline (247.097 us; speedup 1.0000x reference)
//
#include <hip/hip_runtime.h>

// N=64, T=2048, D=256, fp32. out = [context (N*D)] ++ [norm_attention (N*T)].
// softmax+mask+renorm == softmax restricted to t < lens[n]; attn == 0 past lens.
// 3 kernels:
//  K0 init: prefix[n] = sum of ceil(L/64) -> compact valid-chunk work list.
//  K1 fused (1-D grid, compacted): block b -> (n,c) via prefix binary search;
//     e = K·q (4 rows/wave-pass, 16-lane reduce), chunk (m,Z), p=exp(e-m)->ws,
//     partial context O_c = p·V -> ws. K/V nontemporal.
//  K2 merge (4,N): s_c = exp(m_c-m)/Z; attn = p*s_c (0 past lens);
//     context = sum_c s_c * O_c.

#define N_B 64
#define T_S 2048
#define D_S 256
#define TPB 256
#define RC 64
#define NC (T_S / RC)  // 32
#define NBLK (NC * N_B)  // 2048 max chunks

typedef __attribute__((ext_vector_type(4))) float f4;
typedef __attribute__((ext_vector_type(2))) float f2;

__device__ __forceinline__ f4 ntload4(const float* p) {
  return __builtin_nontemporal_load((const f4*)p);
}
__device__ __forceinline__ f4 fma4(float s, f4 a, f4 b) {
  b.x = fmaf(s, a.x, b.x);
  b.y = fmaf(s, a.y, b.y);
  b.z = fmaf(s, a.z, b.z);
  b.w = fmaf(s, a.w, b.w);
  return b;
}

// ---- K0: prefix[0]=0; prefix[i+1]=sum_{j<=i} ceil(lens[j]/RC). 1 block/64thr.
__global__ void init_kernel(const int* __restrict__ lens,
                            int* __restrict__ prefix) {
  const int t = threadIdx.x;  // 64 threads
  int x = (t < N_B) ? (lens[t] + RC - 1) / RC : 0;
#pragma unroll
  for (int off = 1; off < 64; off <<= 1) {
    const int y = __shfl_up(x, off, 64);
    if (t >= off) x += y;
  }
  if (t < N_B) prefix[t + 1] = x;
  if (t == 0) prefix[0] = 0;
}

// ---- K1: fused energy + chunk softmax + partial context, compacted grid ----
__global__ __launch_bounds__(TPB) void fused_kernel(
    const float* __restrict__ q, const float* __restrict__ k,
    const float* __restrict__ v, const int* __restrict__ lens,
    const int* __restrict__ prefix, float* __restrict__ p_out,
    float2* __restrict__ mzc, float* __restrict__ Oc) {
  const int tid = threadIdx.x;
  const int lane = tid & 63, wave = tid >> 6;

  __shared__ int P[N_B + 1];
  __shared__ f4 q_sh[64];
  __shared__ float e_sh[RC];
  __shared__ float p_sh[RC];
  __shared__ f4 part[TPB];

  if (tid < N_B + 1) P[tid] = prefix[tid];
  __syncthreads();
  const int b = blockIdx.x;
  if (b >= P[N_B]) return;
  // largest n with P[n] <= b  (uniform binary search, LDS broadcast reads)
  int lo = 0, hi = N_B;
  while (hi - lo > 1) {
    const int mid = (lo + hi) >> 1;
    if (P[mid] <= b) lo = mid; else hi = mid;
  }
  const int n = lo, c = b - P[lo];
  const int L = lens[n];
  const int t0 = c * RC;            // guaranteed < L
  const int tend = min(t0 + RC, L);

  if (tid < 64) q_sh[tid] = ((const f4*)(q + (size_t)n * D_S))[tid];
  if (tid < RC) e_sh[tid] = -1e30f;
  __syncthreads();

  // ---- phase 1: energies. Wave owns 16 rows; 4 rows per pass, lane =
  // (quarter qd -> row, sublane s -> d-quarter). 16 independent loads/wave.
  {
    const int s = lane & 15, qd = lane >> 4;
    const float* kb = k + (size_t)n * T_S * D_S + s * 4;
    const int rbase = t0 + wave * 16 + qd;
#pragma unroll
    for (int g = 0; g < 4; ++g) {
      const int r = rbase + g * 4;  // always < T_S: loads in-bounds
      const float* krow = kb + (size_t)r * D_S;
      float acc = 0.f;
#pragma unroll
      for (int i = 0; i < 4; ++i) {
        const f4 kv = ntload4(krow + i * 64);
        const f4 qv = q_sh[i * 16 + s];
        acc = fmaf(kv.x, qv.x, acc);
        acc = fmaf(kv.y, qv.y, acc);
        acc = fmaf(kv.z, qv.z, acc);
        acc = fmaf(kv.w, qv.w, acc);
      }
#pragma unroll
      for (int off = 8; off > 0; off >>= 1) acc += __shfl_xor(acc, off, 64);
      if (s == 0 && r < tend) e_sh[r - t0] = acc;
    }
  }
  __syncthreads();

  // ---- phase 2: chunk-local softmax partials (invalid rows e=-1e30 -> p=0)
  if (wave == 0) {
    const float e = e_sh[lane];
    float m = e;
#pragma unroll
    for (int off = 32; off > 0; off >>= 1) m = fmaxf(m, __shfl_xor(m, off, 64));
    const float pv = __expf(e - m);
    float z = pv;
#pragma unroll
    for (int off = 32; off > 0; off >>= 1) z += __shfl_xor(z, off, 64);
    p_sh[lane] = pv;
    p_out[(size_t)n * T_S + t0 + lane] = pv;
    if (lane == 0) mzc[n * NC + c] = make_float2(m, z);
  }
  __syncthreads();

  // ---- phase 3: O_c = sum_t p_t * v_t. Fixed 16-iter fully-unrolled loop,
  // p=0 kills rows past tend (loads stay in-bounds: r < T_S).
  const int dg = tid & 63, tg = tid >> 6;
  const float* vb = v + (size_t)n * T_S * D_S + (size_t)t0 * D_S + dg * 4;
  f4 a0 = {0.f, 0.f, 0.f, 0.f}, a1 = a0, a2 = a0, a3 = a0;
#pragma unroll
  for (int j = 0; j < 4; ++j) {
    const int r0 = j * 16 + tg;
    const f4 v0 = ntload4(vb + (size_t)r0 * D_S);
    const f4 v1 = ntload4(vb + (size_t)(r0 + 4) * D_S);
    const f4 v2 = ntload4(vb + (size_t)(r0 + 8) * D_S);
    const f4 v3 = ntload4(vb + (size_t)(r0 + 12) * D_S);
    a0 = fma4(p_sh[r0], v0, a0);
    a1 = fma4(p_sh[r0 + 4], v1, a1);
    a2 = fma4(p_sh[r0 + 8], v2, a2);
    a3 = fma4(p_sh[r0 + 12], v3, a3);
  }
  part[tid] = (a0 + a1) + (a2 + a3);
  __syncthreads();
  if (tg == 0) {
    const f4 r = part[dg] + part[dg + 64] + part[dg + 128] + part[dg + 192];
    ((f4*)(Oc + ((size_t)(n * NC + c)) * D_S))[dg] = r;
  }
}

// ---- K2: merge. Block (cx,n): attn t-slice [cx*512, +512), ctx d-slice
// [cx*64, +64). Chunk stats recomputed per block (L2-hot, 16 KB total).
__global__ __launch_bounds__(TPB) void merge_kernel(
    const int* __restrict__ lens, const float* __restrict__ p_in,
    const float2* __restrict__ mzc, const float* __restrict__ Oc,
    float* __restrict__ out_ctx, float* __restrict__ out_attn) {
  const int n = blockIdx.y, cx = blockIdx.x;
  const int L = lens[n];
  const int nc = (L + RC - 1) / RC;
  const int tid = threadIdx.x;
  __shared__ float s_sh[NC];
  __shared__ float cpart[TPB];

  if (tid < 64) {
    float m = -1e30f, z = 0.f;
    if (tid < nc) {
      const float2 mz = mzc[n * NC + tid];
      m = mz.x;
      z = mz.y;
    }
    float M = m;
#pragma unroll
    for (int off = 32; off > 0; off >>= 1) M = fmaxf(M, __shfl_xor(M, off, 64));
    const float sc = __expf(m - M);  // 0 for invalid chunks
    float zs = z * sc;
#pragma unroll
    for (int off = 32; off > 0; off >>= 1) zs += __shfl_xor(zs, off, 64);
    if (tid < NC) s_sh[tid] = sc / zs;
  }
  __syncthreads();

  // attention slice (float2 per thread; zeros past lens, no read past lens)
  {
    const int t = cx * (T_S / 4) + tid * 2;
    f2 a = {0.f, 0.f};
    if (t < L) {
      const f2 p = *(const f2*)(p_in + (size_t)n * T_S + t);
      const float sc = s_sh[t >> 6];
      a.x = p.x * sc;
      a.y = (t + 1 < L) ? p.y * sc : 0.f;
    }
    *(f2*)(out_attn + (size_t)n * T_S + t) = a;
  }

  // context slice: thread (d = cx*64 + (tid&63), chunk-group tid>>6 of 4);
  // only valid chunks are read.
  {
    const int d = cx * 64 + (tid & 63);
    const int cg = tid >> 6;
    const float* ob = Oc + (size_t)n * NC * D_S + d;
    float acc = 0.f;
    for (int cc = cg; cc < nc; cc += 4)
      acc = fmaf(s_sh[cc], ob[(size_t)cc * D_S], acc);
    cpart[tid] = acc;
    __syncthreads();
    if (tid < 64)
      out_ctx[(size_t)n * D_S + d] =
          (cpart[tid] + cpart[tid + 64]) + (cpart[tid + 128] + cpart[tid + 192]);
  }
}

extern "C" void kernel_launch(void* const* d_in, const int* in_sizes, int n_in,
                              void* d_out, int out_size, void* d_ws,
                              size_t ws_size, hipStream_t stream) {
  const float* query = (const float*)d_in[0];
  const float* key = (const float*)d_in[1];
  const float* value = (const float*)d_in[2];
  const int* lens = (const int*)d_in[3];

  float* out_ctx = (float*)d_out;               // N*D
  float* out_attn = (float*)d_out + N_B * D_S;  // N*T

  float* p = (float*)d_ws;                                 // N*T (512 KB)
  float2* mzc = (float2*)(p + (size_t)N_B * T_S);          // N*NC (16 KB)
  float* Oc = (float*)(mzc + N_B * NC);                    // N*NC*D (2 MB)
  int* prefix = (int*)(Oc + (size_t)N_B * NC * D_S);       // 65 ints

  init_kernel<<<1, 64, 0, stream>>>(lens, prefix);
  fused_kernel<<<NBLK, TPB, 0, stream>>>(query, key, value, lens, prefix, p,
                                         mzc, Oc);
  const dim3 grid2(4, N_B);
  merge_kernel<<<grid2, TPB, 0, stream>>>(lens, p, mzc, Oc, out_ctx, out_attn);
}